// Round 7
// baseline (236.988 us; speedup 1.0000x reference)
//
#include <hip/hip_runtime.h>
#include <hip/hip_bf16.h>
#include <math.h>

// Problem: B=32, N=128, S=64, D=512
// Output: [B,N] f32, each row sorted descending.
// Round 7: 6 launches. k2_fused = [32 chain blocks (h->cond->q->qk per b,
// intra-block syncthreads) dispatched FIRST] + [4096 BW-bound sim blocks]
// + convWb prologue. Score moved to k_vsum. k4 double-buffered.

#define BB 32
#define NN 128
#define SS 64
#define DD 512

typedef __attribute__((ext_vector_type(8))) short short8;
typedef __attribute__((ext_vector_type(4))) float f32x4;

__device__ __forceinline__ ushort f2bf(float f) {
    unsigned u = __float_as_uint(f);
    unsigned r = (u + 0x7fffu + ((u >> 16) & 1u)) >> 16;
    return (ushort)r;
}

// Batched wave-dot: 4 rows of W (stride ldw) dotted with x (in regs xa/xb).
// 8 float4 loads in flight before the serial shuffle reduces.
__device__ __forceinline__ void wave_dot512x4(
    const float* __restrict__ w, size_t ldw, float4 xa, float4 xb,
    int lane, float out[4]) {
    float4 ra[4], rb[4];
#pragma unroll
    for (int r = 0; r < 4; ++r) {
        const float4* row = reinterpret_cast<const float4*>(w + (size_t)r * ldw);
        ra[r] = row[lane * 2];
        rb[r] = row[lane * 2 + 1];
    }
#pragma unroll
    for (int r = 0; r < 4; ++r) {
        float s = ra[r].x * xa.x + ra[r].y * xa.y + ra[r].z * xa.z + ra[r].w * xa.w
                + rb[r].x * xb.x + rb[r].y * xb.y + rb[r].z * xb.z + rb[r].w * xb.w;
#pragma unroll
        for (int off = 32; off; off >>= 1) s += __shfl_xor(s, off);
        out[r] = s;
    }
}

// Batched matvec: Y[b][j] = act(W[j] . X[b] + bias[j]); grid (R/16, B).
__global__ __launch_bounds__(256) void bmv(
    const float* __restrict__ W, int ldw, const float* __restrict__ bias,
    const float* __restrict__ Xa, float* __restrict__ Y, int R, int act) {
    __shared__ __align__(16) float xl[DD];
    int b = blockIdx.y, tid = threadIdx.x, lane = tid & 63, wave = tid >> 6;
    const float* src = Xa + (size_t)b * DD;
    for (int i = tid; i < DD; i += 256) xl[i] = src[i];
    __syncthreads();
    float4 xa = reinterpret_cast<const float4*>(xl)[lane * 2];
    float4 xb = reinterpret_cast<const float4*>(xl)[lane * 2 + 1];
    int j0 = blockIdx.x * 16 + wave * 4;
    float s[4];
    wave_dot512x4(W + (size_t)j0 * ldw, ldw, xa, xb, lane, s);
    if (lane < 4) {
        int j = j0 + lane;
        float v = s[lane];
        if (bias) v += bias[j];
        if (act == 1) v = v / (1.f + expf(-v));  // silu
        Y[(size_t)b * R + j] = v;
    }
}

// k2_fused: blk<32 -> per-b cond chain; else sim/argmax/gather (+convWb).
__global__ __launch_bounds__(256) void k2_fused(
    const int* __restrict__ ts, const float* __restrict__ pe,
    const float* __restrict__ fusion, const float* __restrict__ tif,
    const float* __restrict__ Wt1, const float* __restrict__ bt1,
    const float* __restrict__ Wt2, const float* __restrict__ bt2,
    const float* __restrict__ Wq, const float* __restrict__ Wk,
    const float* __restrict__ Wd1, ushort* __restrict__ Wb,
    float* __restrict__ cond, float* __restrict__ qk,
    float* __restrict__ tif_best, ushort* __restrict__ abf) {
    __shared__ __align__(16) float xin[DD];
    __shared__ __align__(16) float hl[DD];
    __shared__ __align__(16) float cl[DD];
    __shared__ __align__(16) float ql[DD];
    __shared__ __align__(16) float paux[4][DD >> 2];  // 4 waves x 128... see S4
    __shared__ float bv_s[4];
    __shared__ int bi_s[4];
    __shared__ int bidx_s;
    int blk = blockIdx.x, tid = threadIdx.x, lane = tid & 63, wave = tid >> 6;

    if (blk < 32) {
        // ---------------- cond chain for b = blk ----------------
        int b = blk;
        // S1: h = silu(Wt1 @ pe[ts[b]] + bt1)
        {
            const float* per = pe + (size_t)ts[b] * DD;
            for (int i = tid; i < DD; i += 256) xin[i] = per[i];
        }
        __syncthreads();
        {
            float4 xa = reinterpret_cast<const float4*>(xin)[lane * 2];
            float4 xb = reinterpret_cast<const float4*>(xin)[lane * 2 + 1];
            for (int j0 = wave * 128; j0 < wave * 128 + 128; j0 += 4) {
                float s[4];
                wave_dot512x4(Wt1 + (size_t)j0 * DD, DD, xa, xb, lane, s);
                if (lane < 4) {
                    float v = s[lane] + bt1[j0 + lane];
                    hl[j0 + lane] = v / (1.f + expf(-v));
                }
            }
        }
        __syncthreads();
        // S2: cond = Wt2 @ h + bt2
        {
            float4 xa = reinterpret_cast<const float4*>(hl)[lane * 2];
            float4 xb = reinterpret_cast<const float4*>(hl)[lane * 2 + 1];
            for (int j0 = wave * 128; j0 < wave * 128 + 128; j0 += 4) {
                float s[4];
                wave_dot512x4(Wt2 + (size_t)j0 * DD, DD, xa, xb, lane, s);
                if (lane < 4) {
                    float v = s[lane] + bt2[j0 + lane];
                    cl[j0 + lane] = v;
                    cond[(size_t)b * DD + j0 + lane] = v;
                }
            }
        }
        __syncthreads();
        // S3: q = Wq @ (fusion + cond)  (LDS only)
        for (int i = tid; i < DD; i += 256) xin[i] = fusion[(size_t)b * DD + i] + cl[i];
        __syncthreads();
        {
            float4 xa = reinterpret_cast<const float4*>(xin)[lane * 2];
            float4 xb = reinterpret_cast<const float4*>(xin)[lane * 2 + 1];
            for (int j0 = wave * 128; j0 < wave * 128 + 128; j0 += 4) {
                float s[4];
                wave_dot512x4(Wq + (size_t)j0 * DD, DD, xa, xb, lane, s);
                if (lane < 4) ql[j0 + lane] = s[lane];
            }
        }
        __syncthreads();
        // S4: qk = Wk^T @ q. Each wave covers all 512 cols (8/lane) over its
        // 128 rows; partials combined through hl/cl (reused as 2KB scratch x2).
        {
            float a8[8] = {0, 0, 0, 0, 0, 0, 0, 0};
            for (int j = wave * 128; j < wave * 128 + 128; ++j) {
                float qj = ql[j];
                const float4* row = reinterpret_cast<const float4*>(Wk + ((size_t)j << 9));
                float4 r0 = row[lane * 2];
                float4 r1 = row[lane * 2 + 1];
                a8[0] += qj * r0.x; a8[1] += qj * r0.y;
                a8[2] += qj * r0.z; a8[3] += qj * r0.w;
                a8[4] += qj * r1.x; a8[5] += qj * r1.y;
                a8[6] += qj * r1.z; a8[7] += qj * r1.w;
            }
            // partials: wave 0/1 -> hl, wave 2/3 -> cl (after adding pairwise)
            // first waves 0,2 write; then waves 1,3 add; then combine.
            if ((wave & 1) == 0) {
#pragma unroll
                for (int e = 0; e < 8; ++e)
                    (wave == 0 ? hl : cl)[lane * 8 + e] = a8[e];
            }
            __syncthreads();
            if (wave & 1) {
#pragma unroll
                for (int e = 0; e < 8; ++e)
                    (wave == 1 ? hl : cl)[lane * 8 + e] += a8[e];
            }
            __syncthreads();
            for (int c = tid; c < DD; c += 256)
                qk[(size_t)b * DD + c] = hl[c] + cl[c];
        }
        return;
    }

    // ---------------- sim / argmax / gather ----------------
    int bn = blk - 32, b = bn >> 7;
    // convWb prologue spread over first 1024 sim blocks
    if (bn < 1024) {
        int idx = (bn * 256 + tid) * 2;
        int r = idx >> 9, k = idx & 511;
        float2 v = *reinterpret_cast<const float2*>(Wd1 + (size_t)r * 1024 + 512 + k);
        ushort2 o = {f2bf(v.x), f2bf(v.y)};
        *reinterpret_cast<ushort2*>(Wb + (size_t)r * 512 + k) = o;
    }
    for (int i = tid; i < DD; i += 256) xin[i] = fusion[(size_t)b * DD + i];
    __syncthreads();
    float4 xa = reinterpret_cast<const float4*>(xin)[lane * 2];
    float4 xb = reinterpret_cast<const float4*>(xin)[lane * 2 + 1];
    const float* base = tif + (size_t)bn * SS * DD;
    float bv = -INFINITY;
    int bi = 0;
    for (int s0 = wave * 16; s0 < wave * 16 + 16; s0 += 4) {
        float sv[4];
        wave_dot512x4(base + (size_t)s0 * DD, DD, xa, xb, lane, sv);
#pragma unroll
        for (int r = 0; r < 4; ++r)
            if (sv[r] > bv) { bv = sv[r]; bi = s0 + r; }  // strict >: first max
    }
    if (lane == 0) { bv_s[wave] = bv; bi_s[wave] = bi; }
    __syncthreads();
    if (tid == 0) {
        float v = bv_s[0]; int i0 = bi_s[0];
        for (int w = 1; w < 4; w++)
            if (bv_s[w] > v) { v = bv_s[w]; i0 = bi_s[w]; }  // waves ascend in s
        bidx_s = i0;
    }
    __syncthreads();
    const float* src = base + (size_t)bidx_s * DD;
    for (int i = tid; i < DD; i += 256) {
        float vv = src[i];
        tif_best[(size_t)bn * DD + i] = vv;
        abf[(size_t)bn * DD + i] = f2bf(vv);
    }
}

// k_vsum: score (from qk . tif_best + x) + softmax + wout + vsum. grid (2, B).
__global__ __launch_bounds__(256) void k_vsum(
    const float* __restrict__ qk, const float* __restrict__ x,
    const float* __restrict__ tif_best, const float* __restrict__ cond,
    float* __restrict__ wout, float* __restrict__ vsum) {
    __shared__ __align__(16) float qkl[DD];
    __shared__ float wl[NN];
    __shared__ float redm[2], reds[2];
    int b = blockIdx.y, tid = threadIdx.x, lane = tid & 63, wave = tid >> 6;
    for (int i = tid; i < DD; i += 256) qkl[i] = qk[(size_t)b * DD + i];
    __syncthreads();
    {
        float4 xa = reinterpret_cast<const float4*>(qkl)[lane * 2];
        float4 xb = reinterpret_cast<const float4*>(qkl)[lane * 2 + 1];
        for (int n0 = wave * 32; n0 < wave * 32 + 32; n0 += 4) {
            float s[4];
            wave_dot512x4(tif_best + ((size_t)(b * NN + n0)) * DD, DD, xa, xb, lane, s);
            if (lane < 4) wl[n0 + lane] = s[lane] + x[b * NN + n0 + lane];
        }
    }
    __syncthreads();
    float v = 0.f;
    if (tid < NN) {
        v = wl[tid];
        float m = v;
#pragma unroll
        for (int off = 32; off; off >>= 1) m = fmaxf(m, __shfl_xor(m, off));
        if (lane == 0) redm[wave] = m;
    }
    __syncthreads();
    float m = fmaxf(redm[0], redm[1]);
    float e = 0.f;
    if (tid < NN) {
        e = expf(v - m);
        float s = e;
#pragma unroll
        for (int off = 32; off; off >>= 1) s += __shfl_xor(s, off);
        if (lane == 0) reds[wave] = s;
    }
    __syncthreads();
    if (tid < NN) wl[tid] = e;
    __syncthreads();
    float inv = 1.f / (reds[0] + reds[1]);
    if (blockIdx.x == 0 && tid < NN) wout[b * NN + tid] = wl[tid] * inv;
    int d = blockIdx.x * 256 + tid;
    const float* base = tif_best + (size_t)b * NN * DD + d;
    float s = 0.f;
#pragma unroll 8
    for (int n = 0; n < NN; n++) s += wl[n] * base[(size_t)n * DD];
    vsum[(size_t)b * DD + d] = s * inv + cond[(size_t)b * DD + d];
}

// K4: bf16 MFMA GEMM C[4096,1024] = Abf[4096,512] x Wb^T, fused u+relu+Wd2.
// Double-buffered LDS (2-phase): STAGE(next, buf^1) issued BEFORE compute(buf).
__global__ __launch_bounds__(256) void k4_mfma(
    const ushort* __restrict__ Abf, const ushort* __restrict__ Wb,
    const float* __restrict__ Wd1, const float* __restrict__ bd1,
    const float* __restrict__ ne, const float* __restrict__ Wd2,
    float* __restrict__ p_part) {
    __shared__ ushort aS[2][128 * 64];  // 2 x 16 KB
    __shared__ ushort bS[2][128 * 64];
    __shared__ __align__(16) float nel[DD];
    __shared__ float uloc[128];
    int tid = threadIdx.x, l = tid & 63, w = tid >> 6;
    int m0 = blockIdx.x * 128, n0 = blockIdx.y * 128;
    int b = blockIdx.x;  // BM=128 == N rows per batch
    int wm = w >> 1, wn = w & 1;

    for (int i = tid; i < DD; i += 256) nel[i] = ne[(size_t)b * DD + i];
    __syncthreads();
    float4 na = reinterpret_cast<const float4*>(nel)[l * 2];
    float4 nb = reinterpret_cast<const float4*>(nel)[l * 2 + 1];

#define STAGE(K0, BUF)                                                         \
    {                                                                          \
        _Pragma("unroll") for (int i = 0; i < 4; ++i) {                        \
            int L = i * 4096 + w * 1024 + l * 16;                              \
            int row = L >> 7;                                                  \
            int bo = L & 127;                                                  \
            int sb = bo ^ ((row & 7) << 4);                                    \
            const ushort* ga = Abf + (size_t)(m0 + row) * DD + (K0) + (sb >> 1); \
            const ushort* gb = Wb + (size_t)(n0 + row) * DD + (K0) + (sb >> 1);  \
            __builtin_amdgcn_global_load_lds(                                  \
                (const __attribute__((address_space(1))) void*)ga,             \
                (__attribute__((address_space(3))) void*)(aS[BUF] + i * 2048 + w * 512), \
                16, 0, 0);                                                     \
            __builtin_amdgcn_global_load_lds(                                  \
                (const __attribute__((address_space(1))) void*)gb,             \
                (__attribute__((address_space(3))) void*)(bS[BUF] + i * 2048 + w * 512), \
                16, 0, 0);                                                     \
        }                                                                      \
    }

    STAGE(0, 0);
    // u-prologue overlaps stage-0: u[r] = Wd1_a[n0+r].ne[b] + bd1[n0+r]
    for (int j0 = 0; j0 < 32; j0 += 4) {
        int r = w * 32 + j0;
        float s[4];
        wave_dot512x4(Wd1 + (size_t)(n0 + r) * 1024, 1024, na, nb, l, s);
        if (l < 4) uloc[r + l] = s[l] + bd1[n0 + r + l];
    }
    __syncthreads();

    f32x4 acc[4][4];
#pragma unroll
    for (int i = 0; i < 4; i++)
#pragma unroll
        for (int j = 0; j < 4; j++) acc[i][j] = (f32x4){0.f, 0.f, 0.f, 0.f};

    int cur = 0;
    for (int k0 = 0; k0 < DD; k0 += 64) {
        if (k0 + 64 < DD) STAGE(k0 + 64, cur ^ 1);  // prefetch into other buf
#pragma unroll
        for (int kk = 0; kk < 2; ++kk) {
            short8 af[4], bf[4];
#pragma unroll
            for (int f = 0; f < 4; ++f) {
                int ra = wm * 64 + f * 16 + (l & 15);
                int boa = (((l >> 4) * 16 + kk * 64)) ^ ((ra & 7) << 4);
                af[f] = *reinterpret_cast<const short8*>(&aS[cur][ra * 64 + (boa >> 1)]);
                int rb = wn * 64 + f * 16 + (l & 15);
                int bob = (((l >> 4) * 16 + kk * 64)) ^ ((rb & 7) << 4);
                bf[f] = *reinterpret_cast<const short8*>(&bS[cur][rb * 64 + (bob >> 1)]);
            }
#pragma unroll
            for (int fm = 0; fm < 4; ++fm)
#pragma unroll
                for (int fn = 0; fn < 4; ++fn)
                    acc[fm][fn] = __builtin_amdgcn_mfma_f32_16x16x32_bf16(
                        af[fm], bf[fn], acc[fm][fn], 0, 0, 0);
        }
        __syncthreads();  // drains stage loads (vmcnt0) + LDS reads
        cur ^= 1;
    }
#undef STAGE
#pragma unroll
    for (int fm = 0; fm < 4; ++fm) {
#pragma unroll
        for (int reg = 0; reg < 4; ++reg) {
            float pp = 0.f;
#pragma unroll
            for (int fn = 0; fn < 4; ++fn) {
                int rl = wn * 64 + fn * 16 + (l & 15);
                float hh = acc[fm][fn][reg] + uloc[rl];
                if (hh > 0.f) pp += Wd2[n0 + rl] * hh;
            }
#pragma unroll
            for (int off = 1; off < 16; off <<= 1) pp += __shfl_xor(pp, off);
            if ((l & 15) == 0) {
                int m = m0 + wm * 64 + fm * 16 + (l >> 4) * 4 + reg;
                p_part[(size_t)m * 16 + blockIdx.y * 2 + wn] = pp;
            }
        }
    }
}

// K5: p = sum(p_part) + bd2 + w; bitonic sort 128 descending per b.
__global__ __launch_bounds__(128) void k5_sort(
    const float* __restrict__ p_part, const float* __restrict__ wout,
    const float* __restrict__ bd2, float* __restrict__ out) {
    __shared__ float v[NN];
    int b = blockIdx.x, tid = threadIdx.x;
    int bn = b * NN + tid;
    float s = bd2[0] + wout[bn];
#pragma unroll
    for (int c = 0; c < 16; c++) s += p_part[(size_t)bn * 16 + c];
    v[tid] = s;
    __syncthreads();
    for (int k = 2; k <= NN; k <<= 1) {
        for (int j = k >> 1; j > 0; j >>= 1) {
            int ixj = tid ^ j;
            if (ixj > tid) {
                float a = v[tid], bb2 = v[ixj];
                bool desc = (tid & k) == 0;
                if (desc ? (a < bb2) : (a > bb2)) { v[tid] = bb2; v[ixj] = a; }
            }
            __syncthreads();
        }
    }
    out[bn] = v[tid];
}

extern "C" void kernel_launch(void* const* d_in, const int* in_sizes, int n_in,
                              void* d_out, int out_size, void* d_ws, size_t ws_size,
                              hipStream_t stream) {
    const float* x      = (const float*)d_in[0];
    const int*   ts     = (const int*)d_in[1];
    const float* fusion = (const float*)d_in[2];
    const float* tif    = (const float*)d_in[3];
    const float* pe     = (const float*)d_in[4];
    const float* Wq     = (const float*)d_in[5];
    const float* Wk     = (const float*)d_in[6];
    const float* Wv     = (const float*)d_in[7];
    const float* Wp     = (const float*)d_in[8];
    const float* bp     = (const float*)d_in[9];
    const float* Wt1    = (const float*)d_in[10];
    const float* bt1    = (const float*)d_in[11];
    const float* Wt2    = (const float*)d_in[12];
    const float* bt2    = (const float*)d_in[13];
    const float* Wd1    = (const float*)d_in[14];
    const float* bd1    = (const float*)d_in[15];
    const float* Wd2    = (const float*)d_in[16];
    const float* bd2    = (const float*)d_in[17];

    float* ws = (float*)d_ws;
    float* cond     = ws;                    // 16384
    float* qk       = cond + 16384;          // 16384
    float* wout     = qk + 16384;            // 4096
    float* vsum     = wout + 4096;           // 16384
    float* ve       = vsum + 16384;          // 16384
    float* ne       = ve + 16384;            // 16384
    float* p_part   = ne + 16384;            // 65536
    float* tif_best = p_part + 65536;        // 2097152 (8 MB)
    ushort* Abf     = (ushort*)(tif_best + 2097152);  // 4 MB
    ushort* Wb      = Abf + 2097152;         // 1 MB
    float* out = (float*)d_out;

    // k2_fused: 32 chain blocks (first) + 4096 sim blocks (+convWb)
    hipLaunchKernelGGL(k2_fused, dim3(32 + BB * NN), dim3(256), 0, stream,
                       ts, pe, fusion, tif, Wt1, bt1, Wt2, bt2, Wq, Wk,
                       Wd1, Wb, cond, qk, tif_best, Abf);

    // score + softmax + vsum
    hipLaunchKernelGGL(k_vsum, dim3(2, BB), dim3(256), 0, stream,
                       qk, x, tif_best, cond, wout, vsum);

    // ve = Wv @ vsum ; ne = Wp @ ve + bp
    hipLaunchKernelGGL(bmv, dim3(32, BB), dim3(256), 0, stream,
                       Wv, DD, nullptr, vsum, ve, DD, 0);
    hipLaunchKernelGGL(bmv, dim3(32, BB), dim3(256), 0, stream,
                       Wp, DD, bp, ve, ne, DD, 0);

    // decode GEMM (MFMA, dbuf, u folded) + sort
    hipLaunchKernelGGL(k4_mfma, dim3(32, 8), dim3(256), 0, stream,
                       Abf, Wb, Wd1, bd1, ne, Wd2, p_part);
    hipLaunchKernelGGL(k5_sort, dim3(BB), dim3(128), 0, stream,
                       p_part, wout, bd2, out);
}

// Round 8
// 211.903 us; speedup vs baseline: 1.1184x; 1.1184x over previous
//
#include <hip/hip_runtime.h>
#include <hip/hip_bf16.h>
#include <math.h>

// Problem: B=32, N=128, S=64, D=512
// Output: [B,N] f32, each row sorted descending.
// Round 8: 4 launches: memset(flags), k2_fused (256 chain helpers + 4096 sim),
// k4_fused (256 attn helpers + 256 MFMA GEMM blocks), k5_sort.
// Helper sync: per-(b,stage) flag counters; producer release fetch_add,
// consumer relaxed poll + one acquire fence (round-5-proven pattern; only
// 8 pollers per flag — the round-4 failure mode was acquire-in-loop x1024).

#define BB 32
#define NN 128
#define SS 64
#define DD 512

typedef __attribute__((ext_vector_type(8))) short short8;
typedef __attribute__((ext_vector_type(4))) float f32x4;

__device__ __forceinline__ ushort f2bf(float f) {
    unsigned u = __float_as_uint(f);
    unsigned r = (u + 0x7fffu + ((u >> 16) & 1u)) >> 16;
    return (ushort)r;
}

// flag(b, s) at flags[(b*8+s)*16]  (64B padding per flag)
__device__ __forceinline__ unsigned* flag_at(unsigned* fl, int b, int s) {
    return fl + (size_t)(b * 8 + s) * 16;
}
__device__ __forceinline__ void flag_add(unsigned* f) {
    __syncthreads();  // all stores of this block done
    if (threadIdx.x == 0)
        __hip_atomic_fetch_add(f, 1u, __ATOMIC_RELEASE, __HIP_MEMORY_SCOPE_AGENT);
}
__device__ __forceinline__ void flag_wait(unsigned* f, unsigned target) {
    if (threadIdx.x == 0) {
        while (__hip_atomic_load(f, __ATOMIC_RELAXED, __HIP_MEMORY_SCOPE_AGENT) < target)
            __builtin_amdgcn_s_sleep(4);
        __builtin_amdgcn_fence(__ATOMIC_ACQUIRE, "agent");
    }
    __syncthreads();
}

// Batched wave-dot: 4 rows of W (stride ldw) dotted with x (in regs xa/xb).
__device__ __forceinline__ void wave_dot512x4(
    const float* __restrict__ w, size_t ldw, float4 xa, float4 xb,
    int lane, float out[4]) {
    float4 ra[4], rb[4];
#pragma unroll
    for (int r = 0; r < 4; ++r) {
        const float4* row = reinterpret_cast<const float4*>(w + (size_t)r * ldw);
        ra[r] = row[lane * 2];
        rb[r] = row[lane * 2 + 1];
    }
#pragma unroll
    for (int r = 0; r < 4; ++r) {
        float s = ra[r].x * xa.x + ra[r].y * xa.y + ra[r].z * xa.z + ra[r].w * xa.w
                + rb[r].x * xb.x + rb[r].y * xb.y + rb[r].z * xb.z + rb[r].w * xb.w;
#pragma unroll
        for (int off = 32; off; off >>= 1) s += __shfl_xor(s, off);
        out[r] = s;
    }
}

// k2_fused: blk<256 -> chain helper (b=blk>>3, part=blk&7, 64 rows/stage);
//           else sim/argmax/gather (+convWb).
__global__ __launch_bounds__(256) void k2_fused(
    const int* __restrict__ ts, const float* __restrict__ pe,
    const float* __restrict__ fusion, const float* __restrict__ tif,
    const float* __restrict__ Wt1, const float* __restrict__ bt1,
    const float* __restrict__ Wt2, const float* __restrict__ bt2,
    const float* __restrict__ Wq, const float* __restrict__ Wk,
    const float* __restrict__ Wd1, ushort* __restrict__ Wb,
    float* __restrict__ h, float* __restrict__ q,
    float* __restrict__ cond, float* __restrict__ qk,
    float* __restrict__ tif_best, ushort* __restrict__ abf,
    unsigned* __restrict__ flags) {
    __shared__ __align__(16) float xl[DD];
    __shared__ __align__(16) float paux[4][64];
    __shared__ float bv_s[4];
    __shared__ int bi_s[4];
    __shared__ int bidx_s;
    int blk = blockIdx.x, tid = threadIdx.x, lane = tid & 63, wave = tid >> 6;

    if (blk < 256) {
        int b = blk >> 3, part = blk & 7;
        int rows0 = part * 64;
        // ---- S1: h[rows] = silu(Wt1 @ pe[ts[b]] + bt1)
        {
            const float* per = pe + (size_t)ts[b] * DD;
            for (int i = tid; i < DD; i += 256) xl[i] = per[i];
        }
        __syncthreads();
        {
            float4 xa = reinterpret_cast<const float4*>(xl)[lane * 2];
            float4 xb = reinterpret_cast<const float4*>(xl)[lane * 2 + 1];
            for (int j0 = rows0 + wave * 16; j0 < rows0 + wave * 16 + 16; j0 += 4) {
                float s[4];
                wave_dot512x4(Wt1 + (size_t)j0 * DD, DD, xa, xb, lane, s);
                if (lane < 4) {
                    float v = s[lane] + bt1[j0 + lane];
                    h[(size_t)b * DD + j0 + lane] = v / (1.f + expf(-v));
                }
            }
        }
        flag_add(flag_at(flags, b, 0));
        flag_wait(flag_at(flags, b, 0), 8);
        // ---- S2: cond[rows] = Wt2 @ h + bt2
        for (int i = tid; i < DD; i += 256) xl[i] = h[(size_t)b * DD + i];
        __syncthreads();
        {
            float4 xa = reinterpret_cast<const float4*>(xl)[lane * 2];
            float4 xb = reinterpret_cast<const float4*>(xl)[lane * 2 + 1];
            for (int j0 = rows0 + wave * 16; j0 < rows0 + wave * 16 + 16; j0 += 4) {
                float s[4];
                wave_dot512x4(Wt2 + (size_t)j0 * DD, DD, xa, xb, lane, s);
                if (lane < 4)
                    cond[(size_t)b * DD + j0 + lane] = s[lane] + bt2[j0 + lane];
            }
        }
        flag_add(flag_at(flags, b, 1));
        flag_wait(flag_at(flags, b, 1), 8);
        // ---- S3: q[rows] = Wq @ (fusion + cond)
        for (int i = tid; i < DD; i += 256)
            xl[i] = fusion[(size_t)b * DD + i] + cond[(size_t)b * DD + i];
        __syncthreads();
        {
            float4 xa = reinterpret_cast<const float4*>(xl)[lane * 2];
            float4 xb = reinterpret_cast<const float4*>(xl)[lane * 2 + 1];
            for (int j0 = rows0 + wave * 16; j0 < rows0 + wave * 16 + 16; j0 += 4) {
                float s[4];
                wave_dot512x4(Wq + (size_t)j0 * DD, DD, xa, xb, lane, s);
                if (lane < 4) q[(size_t)b * DD + j0 + lane] = s[lane];
            }
        }
        flag_add(flag_at(flags, b, 2));
        flag_wait(flag_at(flags, b, 2), 8);
        // ---- S4: qk[c0..c0+64] = Wk^T @ q  (cols c0 = part*64)
        for (int i = tid; i < DD; i += 256) xl[i] = q[(size_t)b * DD + i];
        __syncthreads();
        {
            int c0 = part * 64;
            float p = 0.f;
            for (int j = wave * 128; j < wave * 128 + 128; ++j)
                p += xl[j] * Wk[(size_t)j * DD + c0 + lane];
            paux[wave][lane] = p;
            __syncthreads();
            if (tid < 64)
                qk[(size_t)b * DD + c0 + tid] =
                    paux[0][tid] + paux[1][tid] + paux[2][tid] + paux[3][tid];
        }
        return;  // kernel-boundary makes qk visible to k4_fused
    }

    // ---------------- sim / argmax / gather ----------------
    int bn = blk - 256, b = bn >> 7;
    // convWb prologue spread over first 1024 sim blocks
    if (bn < 1024) {
        int idx = (bn * 256 + tid) * 2;
        int r = idx >> 9, k = idx & 511;
        float2 v = *reinterpret_cast<const float2*>(Wd1 + (size_t)r * 1024 + 512 + k);
        ushort2 o = {f2bf(v.x), f2bf(v.y)};
        *reinterpret_cast<ushort2*>(Wb + (size_t)r * 512 + k) = o;
    }
    for (int i = tid; i < DD; i += 256) xl[i] = fusion[(size_t)b * DD + i];
    __syncthreads();
    float4 xa = reinterpret_cast<const float4*>(xl)[lane * 2];
    float4 xb = reinterpret_cast<const float4*>(xl)[lane * 2 + 1];
    const float* base = tif + (size_t)bn * SS * DD;
    float bv = -INFINITY;
    int bi = 0;
    for (int s0 = wave * 16; s0 < wave * 16 + 16; s0 += 4) {
        float sv[4];
        wave_dot512x4(base + (size_t)s0 * DD, DD, xa, xb, lane, sv);
#pragma unroll
        for (int r = 0; r < 4; ++r)
            if (sv[r] > bv) { bv = sv[r]; bi = s0 + r; }  // strict >: first max
    }
    if (lane == 0) { bv_s[wave] = bv; bi_s[wave] = bi; }
    __syncthreads();
    if (tid == 0) {
        float v = bv_s[0]; int i0 = bi_s[0];
        for (int w = 1; w < 4; w++)
            if (bv_s[w] > v) { v = bv_s[w]; i0 = bi_s[w]; }  // waves ascend in s
        bidx_s = i0;
    }
    __syncthreads();
    const float* src = base + (size_t)bidx_s * DD;
    for (int i = tid; i < DD; i += 256) {
        float vv = src[i];
        tif_best[(size_t)bn * DD + i] = vv;
        abf[(size_t)bn * DD + i] = f2bf(vv);
    }
}

// k4_fused: blk<256 -> attn helper (score->softmax->vsum->ve->ne);
//           else MFMA GEMM block (g=blk-256: b=g&31, cb=g>>5).
__global__ __launch_bounds__(256) void k4_fused(
    const float* __restrict__ qk, const float* __restrict__ x,
    const float* __restrict__ tif_best, const float* __restrict__ cond,
    const float* __restrict__ Wv, const float* __restrict__ Wp,
    const float* __restrict__ bp,
    const ushort* __restrict__ Abf, const ushort* __restrict__ Wb,
    const float* __restrict__ Wd1, const float* __restrict__ bd1,
    const float* __restrict__ Wd2,
    float* __restrict__ score, float* __restrict__ wout,
    float* __restrict__ vsum, float* __restrict__ ve,
    float* __restrict__ ne, float* __restrict__ p_part,
    unsigned* __restrict__ flags) {
    __shared__ ushort aS[2][128 * 64];  // 32 KB (GEMM path only)
    __shared__ ushort bS[2][128 * 64];  // 32 KB
    __shared__ __align__(16) float vecl[DD];
    __shared__ float wl[NN];
    __shared__ __align__(16) float paux[4][64];
    __shared__ float redm[2], reds[2];
    __shared__ float uloc[128];
    int blk = blockIdx.x, tid = threadIdx.x, lane = tid & 63, wave = tid >> 6;

    if (blk < 256) {
        int b = blk >> 3, part = blk & 7;
        // ---- score: n-slice [part*16, +16): qk . tif_best + x
        for (int i = tid; i < DD; i += 256) vecl[i] = qk[(size_t)b * DD + i];
        __syncthreads();
        {
            float4 xa = reinterpret_cast<const float4*>(vecl)[lane * 2];
            float4 xb = reinterpret_cast<const float4*>(vecl)[lane * 2 + 1];
            int n0 = part * 16 + wave * 4;
            float s[4];
            wave_dot512x4(tif_best + ((size_t)(b * NN + n0)) * DD, DD, xa, xb, lane, s);
            if (lane < 4)
                score[b * NN + n0 + lane] = s[lane] + x[b * NN + n0 + lane];
        }
        flag_add(flag_at(flags, b, 4));
        flag_wait(flag_at(flags, b, 4), 8);
        // ---- softmax (redundant per part)
        float v = 0.f;
        if (tid < NN) {
            v = score[b * NN + tid];
            float m = v;
#pragma unroll
            for (int off = 32; off; off >>= 1) m = fmaxf(m, __shfl_xor(m, off));
            if (lane == 0) redm[wave] = m;
        }
        __syncthreads();
        float m = fmaxf(redm[0], redm[1]);
        float e = 0.f;
        if (tid < NN) {
            e = expf(v - m);
            float s = e;
#pragma unroll
            for (int off = 32; off; off >>= 1) s += __shfl_xor(s, off);
            if (lane == 0) reds[wave] = s;
        }
        __syncthreads();
        float inv = 1.f / (reds[0] + reds[1]);
        if (tid < NN) wl[tid] = e * inv;
        __syncthreads();
        if (part == 0 && tid < NN) wout[b * NN + tid] = wl[tid];
        // ---- vsum: d-slice [part*64, +64)
        {
            int d0 = part * 64;
            float p = 0.f;
            const float* tb = tif_best + (size_t)b * NN * DD + d0 + lane;
            for (int n = wave * 32; n < wave * 32 + 32; ++n)
                p += wl[n] * tb[(size_t)n * DD];
            paux[wave][lane] = p;
            __syncthreads();
            if (tid < 64)
                vsum[(size_t)b * DD + d0 + tid] =
                    paux[0][tid] + paux[1][tid] + paux[2][tid] + paux[3][tid]
                    + cond[(size_t)b * DD + d0 + tid];
        }
        flag_add(flag_at(flags, b, 5));
        flag_wait(flag_at(flags, b, 5), 8);
        // ---- ve: rows [part*64, +64) of Wv @ vsum
        for (int i = tid; i < DD; i += 256) vecl[i] = vsum[(size_t)b * DD + i];
        __syncthreads();
        {
            float4 xa = reinterpret_cast<const float4*>(vecl)[lane * 2];
            float4 xb = reinterpret_cast<const float4*>(vecl)[lane * 2 + 1];
            int r0 = part * 64 + wave * 16;
            for (int j0 = r0; j0 < r0 + 16; j0 += 4) {
                float s[4];
                wave_dot512x4(Wv + (size_t)j0 * DD, DD, xa, xb, lane, s);
                if (lane < 4) ve[(size_t)b * DD + j0 + lane] = s[lane];
            }
        }
        flag_add(flag_at(flags, b, 6));
        flag_wait(flag_at(flags, b, 6), 8);
        // ---- ne: rows of Wp @ ve + bp
        for (int i = tid; i < DD; i += 256) vecl[i] = ve[(size_t)b * DD + i];
        __syncthreads();
        {
            float4 xa = reinterpret_cast<const float4*>(vecl)[lane * 2];
            float4 xb = reinterpret_cast<const float4*>(vecl)[lane * 2 + 1];
            int r0 = part * 64 + wave * 16;
            for (int j0 = r0; j0 < r0 + 16; j0 += 4) {
                float s[4];
                wave_dot512x4(Wp + (size_t)j0 * DD, DD, xa, xb, lane, s);
                if (lane < 4) ne[(size_t)b * DD + j0 + lane] = s[lane] + bp[j0 + lane];
            }
        }
        flag_add(flag_at(flags, b, 7));
        return;
    }

    // ---------------- GEMM block ----------------
    int g = blk - 256;
    int b = g & 31, cb = g >> 5;
    int m0 = b * 128, n0 = cb * 128;
    int l = lane, w = wave;
    int wm = w >> 1, wn = w & 1;

#define STAGE(K0, BUF)                                                         \
    {                                                                          \
        _Pragma("unroll") for (int i = 0; i < 4; ++i) {                        \
            int L = i * 4096 + w * 1024 + l * 16;                              \
            int row = L >> 7;                                                  \
            int bo = L & 127;                                                  \
            int sb = bo ^ ((row & 7) << 4);                                    \
            const ushort* ga = Abf + (size_t)(m0 + row) * DD + (K0) + (sb >> 1); \
            const ushort* gb = Wb + (size_t)(n0 + row) * DD + (K0) + (sb >> 1);  \
            __builtin_amdgcn_global_load_lds(                                  \
                (const __attribute__((address_space(1))) void*)ga,             \
                (__attribute__((address_space(3))) void*)(aS[BUF] + i * 2048 + w * 512), \
                16, 0, 0);                                                     \
            __builtin_amdgcn_global_load_lds(                                  \
                (const __attribute__((address_space(1))) void*)gb,             \
                (__attribute__((address_space(3))) void*)(bS[BUF] + i * 2048 + w * 512), \
                16, 0, 0);                                                     \
        }                                                                      \
    }

    STAGE(0, 0);
    __syncthreads();

    f32x4 acc[4][4];
#pragma unroll
    for (int i = 0; i < 4; i++)
#pragma unroll
        for (int j = 0; j < 4; j++) acc[i][j] = (f32x4){0.f, 0.f, 0.f, 0.f};

    int cur = 0;
    for (int k0 = 0; k0 < DD; k0 += 64) {
        if (k0 + 64 < DD) STAGE(k0 + 64, cur ^ 1);  // prefetch into other buf
#pragma unroll
        for (int kk = 0; kk < 2; ++kk) {
            short8 af[4], bf[4];
#pragma unroll
            for (int f = 0; f < 4; ++f) {
                int ra = wm * 64 + f * 16 + (l & 15);
                int boa = (((l >> 4) * 16 + kk * 64)) ^ ((ra & 7) << 4);
                af[f] = *reinterpret_cast<const short8*>(&aS[cur][ra * 64 + (boa >> 1)]);
                int rb = wn * 64 + f * 16 + (l & 15);
                int bob = (((l >> 4) * 16 + kk * 64)) ^ ((rb & 7) << 4);
                bf[f] = *reinterpret_cast<const short8*>(&bS[cur][rb * 64 + (bob >> 1)]);
            }
#pragma unroll
            for (int fm = 0; fm < 4; ++fm)
#pragma unroll
                for (int fn = 0; fn < 4; ++fn)
                    acc[fm][fn] = __builtin_amdgcn_mfma_f32_16x16x32_bf16(
                        af[fm], bf[fn], acc[fm][fn], 0, 0, 0);
        }
        __syncthreads();  // drains stage loads + LDS reads
        cur ^= 1;
    }
#undef STAGE

    // wait for ne, then compute this block's u-slice
    flag_wait(flag_at(flags, b, 7), 8);
    for (int i = tid; i < DD; i += 256) vecl[i] = ne[(size_t)b * DD + i];
    __syncthreads();
    {
        float4 na = reinterpret_cast<const float4*>(vecl)[l * 2];
        float4 nb = reinterpret_cast<const float4*>(vecl)[l * 2 + 1];
        for (int j0 = 0; j0 < 32; j0 += 4) {
            int r = w * 32 + j0;
            float s[4];
            wave_dot512x4(Wd1 + (size_t)(n0 + r) * 1024, 1024, na, nb, l, s);
            if (l < 4) uloc[r + l] = s[l] + bd1[n0 + r + l];
        }
    }
    __syncthreads();
#pragma unroll
    for (int fm = 0; fm < 4; ++fm) {
#pragma unroll
        for (int reg = 0; reg < 4; ++reg) {
            float pp = 0.f;
#pragma unroll
            for (int fn = 0; fn < 4; ++fn) {
                int rl = wn * 64 + fn * 16 + (l & 15);
                float hh = acc[fm][fn][reg] + uloc[rl];
                if (hh > 0.f) pp += Wd2[n0 + rl] * hh;
            }
#pragma unroll
            for (int off = 1; off < 16; off <<= 1) pp += __shfl_xor(pp, off);
            if ((l & 15) == 0) {
                int m = m0 + wm * 64 + fm * 16 + (l >> 4) * 4 + reg;
                p_part[(size_t)m * 16 + cb * 2 + wn] = pp;
            }
        }
    }
}

// K5: p = sum(p_part) + bd2 + w; bitonic sort 128 descending per b.
__global__ __launch_bounds__(128) void k5_sort(
    const float* __restrict__ p_part, const float* __restrict__ wout,
    const float* __restrict__ bd2, float* __restrict__ out) {
    __shared__ float v[NN];
    int b = blockIdx.x, tid = threadIdx.x;
    int bn = b * NN + tid;
    float s = bd2[0] + wout[bn];
#pragma unroll
    for (int c = 0; c < 16; c++) s += p_part[(size_t)bn * 16 + c];
    v[tid] = s;
    __syncthreads();
    for (int k = 2; k <= NN; k <<= 1) {
        for (int j = k >> 1; j > 0; j >>= 1) {
            int ixj = tid ^ j;
            if (ixj > tid) {
                float a = v[tid], bb2 = v[ixj];
                bool desc = (tid & k) == 0;
                if (desc ? (a < bb2) : (a > bb2)) { v[tid] = bb2; v[ixj] = a; }
            }
            __syncthreads();
        }
    }
    out[bn] = v[tid];
}

extern "C" void kernel_launch(void* const* d_in, const int* in_sizes, int n_in,
                              void* d_out, int out_size, void* d_ws, size_t ws_size,
                              hipStream_t stream) {
    const float* x      = (const float*)d_in[0];
    const int*   ts     = (const int*)d_in[1];
    const float* fusion = (const float*)d_in[2];
    const float* tif    = (const float*)d_in[3];
    const float* pe     = (const float*)d_in[4];
    const float* Wq     = (const float*)d_in[5];
    const float* Wk     = (const float*)d_in[6];
    const float* Wv     = (const float*)d_in[7];
    const float* Wp     = (const float*)d_in[8];
    const float* bp     = (const float*)d_in[9];
    const float* Wt1    = (const float*)d_in[10];
    const float* bt1    = (const float*)d_in[11];
    const float* Wt2    = (const float*)d_in[12];
    const float* bt2    = (const float*)d_in[13];
    const float* Wd1    = (const float*)d_in[14];
    const float* bd1    = (const float*)d_in[15];
    const float* Wd2    = (const float*)d_in[16];
    const float* bd2    = (const float*)d_in[17];

    float* ws = (float*)d_ws;
    float* cond     = ws;                    // 16384
    float* qk       = cond + 16384;          // 16384
    float* h        = qk + 16384;            // 16384
    float* q        = h + 16384;             // 16384
    float* score    = q + 16384;             // 4096
    float* wout     = score + 4096;          // 4096
    float* vsum     = wout + 4096;           // 16384
    float* ve       = vsum + 16384;          // 16384
    float* ne       = ve + 16384;            // 16384
    float* p_part   = ne + 16384;            // 65536
    float* tif_best = p_part + 65536;        // 2097152 (8 MB)
    ushort* Abf     = (ushort*)(tif_best + 2097152);  // 4 MB
    ushort* Wb      = Abf + 2097152;         // 1 MB
    unsigned* flags = (unsigned*)(Wb + 524288);  // 4096 uints (16 KB)
    float* out = (float*)d_out;

    hipMemsetAsync(flags, 0, 16384, stream);

    // chain helpers (first 256 blocks) + sim (4096 blocks) + convWb
    hipLaunchKernelGGL(k2_fused, dim3(256 + BB * NN), dim3(256), 0, stream,
                       ts, pe, fusion, tif, Wt1, bt1, Wt2, bt2, Wq, Wk,
                       Wd1, Wb, h, q, cond, qk, tif_best, Abf, flags);

    // attn helpers (256) + GEMM (256)
    hipLaunchKernelGGL(k4_fused, dim3(512), dim3(256), 0, stream,
                       qk, x, tif_best, cond, Wv, Wp, bp,
                       Abf, Wb, Wd1, bd1, Wd2,
                       score, wout, vsum, ve, ne, p_part, flags);

    hipLaunchKernelGGL(k5_sort, dim3(BB), dim3(128), 0, stream,
                       p_part, wout, bd2, out);
}

// Round 9
// 205.044 us; speedup vs baseline: 1.1558x; 1.0335x over previous
//
#include <hip/hip_runtime.h>
#include <hip/hip_bf16.h>
#include <math.h>

// Problem: B=32, N=128, S=64, D=512
// Output: [B,N] f32, each row sorted descending.
// Round 9 (A/B): ONLY the cond-chain is fused into k2 (flag-synced helpers);
// k4 side reverted to proven separate launches. Flags initialized by a tiny
// kernel (NOT hipMemsetAsync — SDMA fills measured ~10x kernel cost, r8).
// 7 launches: init, k2_fused, k_vsum, bmv(Wv), bmv(Wp), k4(dbuf), k5.

#define BB 32
#define NN 128
#define SS 64
#define DD 512

typedef __attribute__((ext_vector_type(8))) short short8;
typedef __attribute__((ext_vector_type(4))) float f32x4;

__device__ __forceinline__ ushort f2bf(float f) {
    unsigned u = __float_as_uint(f);
    unsigned r = (u + 0x7fffu + ((u >> 16) & 1u)) >> 16;
    return (ushort)r;
}

// flag(b, s) at flags[(b*8+s)*16]  (64B padding per flag)
__device__ __forceinline__ unsigned* flag_at(unsigned* fl, int b, int s) {
    return fl + (size_t)(b * 8 + s) * 16;
}
__device__ __forceinline__ void flag_add(unsigned* f) {
    __syncthreads();  // all stores of this block done
    if (threadIdx.x == 0)
        __hip_atomic_fetch_add(f, 1u, __ATOMIC_RELEASE, __HIP_MEMORY_SCOPE_AGENT);
}
// relaxed poll + one acquire fence after exit (round-5 lesson: ACQUIRE inside
// the loop emits buffer_inv per poll -> chip-wide L2-invalidate storm).
__device__ __forceinline__ void flag_wait(unsigned* f, unsigned target) {
    if (threadIdx.x == 0) {
        while (__hip_atomic_load(f, __ATOMIC_RELAXED, __HIP_MEMORY_SCOPE_AGENT) < target)
            __builtin_amdgcn_s_sleep(4);
        __builtin_amdgcn_fence(__ATOMIC_ACQUIRE, "agent");
    }
    __syncthreads();
}

__global__ __launch_bounds__(256) void k_init(unsigned* __restrict__ flags) {
    flags[blockIdx.x * 256 + threadIdx.x] = 0u;
}

// Batched wave-dot: 4 rows of W (stride ldw) dotted with x (in regs xa/xb).
__device__ __forceinline__ void wave_dot512x4(
    const float* __restrict__ w, size_t ldw, float4 xa, float4 xb,
    int lane, float out[4]) {
    float4 ra[4], rb[4];
#pragma unroll
    for (int r = 0; r < 4; ++r) {
        const float4* row = reinterpret_cast<const float4*>(w + (size_t)r * ldw);
        ra[r] = row[lane * 2];
        rb[r] = row[lane * 2 + 1];
    }
#pragma unroll
    for (int r = 0; r < 4; ++r) {
        float s = ra[r].x * xa.x + ra[r].y * xa.y + ra[r].z * xa.z + ra[r].w * xa.w
                + rb[r].x * xb.x + rb[r].y * xb.y + rb[r].z * xb.z + rb[r].w * xb.w;
#pragma unroll
        for (int off = 32; off; off >>= 1) s += __shfl_xor(s, off);
        out[r] = s;
    }
}

// Batched matvec: Y[b][j] = act(W[j] . X[b] + bias[j]); grid (R/16, B).
__global__ __launch_bounds__(256) void bmv(
    const float* __restrict__ W, int ldw, const float* __restrict__ bias,
    const float* __restrict__ Xa, float* __restrict__ Y, int R, int act) {
    __shared__ __align__(16) float xl[DD];
    int b = blockIdx.y, tid = threadIdx.x, lane = tid & 63, wave = tid >> 6;
    const float* src = Xa + (size_t)b * DD;
    for (int i = tid; i < DD; i += 256) xl[i] = src[i];
    __syncthreads();
    float4 xa = reinterpret_cast<const float4*>(xl)[lane * 2];
    float4 xb = reinterpret_cast<const float4*>(xl)[lane * 2 + 1];
    int j0 = blockIdx.x * 16 + wave * 4;
    float s[4];
    wave_dot512x4(W + (size_t)j0 * ldw, ldw, xa, xb, lane, s);
    if (lane < 4) {
        int j = j0 + lane;
        float v = s[lane];
        if (bias) v += bias[j];
        if (act == 1) v = v / (1.f + expf(-v));  // silu
        Y[(size_t)b * R + j] = v;
    }
}

// k2_fused: blk<256 -> chain helper (b=blk>>3, part=blk&7, 64 rows/stage);
//           else sim/argmax/gather (+convWb).
__global__ __launch_bounds__(256) void k2_fused(
    const int* __restrict__ ts, const float* __restrict__ pe,
    const float* __restrict__ fusion, const float* __restrict__ tif,
    const float* __restrict__ Wt1, const float* __restrict__ bt1,
    const float* __restrict__ Wt2, const float* __restrict__ bt2,
    const float* __restrict__ Wq, const float* __restrict__ Wk,
    const float* __restrict__ Wd1, ushort* __restrict__ Wb,
    float* __restrict__ h, float* __restrict__ q,
    float* __restrict__ cond, float* __restrict__ qk,
    float* __restrict__ tif_best, ushort* __restrict__ abf,
    unsigned* __restrict__ flags) {
    __shared__ __align__(16) float xl[DD];
    __shared__ __align__(16) float paux[4][64];
    __shared__ float bv_s[4];
    __shared__ int bi_s[4];
    __shared__ int bidx_s;
    int blk = blockIdx.x, tid = threadIdx.x, lane = tid & 63, wave = tid >> 6;

    if (blk < 256) {
        int b = blk >> 3, part = blk & 7;
        int rows0 = part * 64;
        // ---- S1: h[rows] = silu(Wt1 @ pe[ts[b]] + bt1)
        {
            const float* per = pe + (size_t)ts[b] * DD;
            for (int i = tid; i < DD; i += 256) xl[i] = per[i];
        }
        __syncthreads();
        {
            float4 xa = reinterpret_cast<const float4*>(xl)[lane * 2];
            float4 xb = reinterpret_cast<const float4*>(xl)[lane * 2 + 1];
            for (int j0 = rows0 + wave * 16; j0 < rows0 + wave * 16 + 16; j0 += 4) {
                float s[4];
                wave_dot512x4(Wt1 + (size_t)j0 * DD, DD, xa, xb, lane, s);
                if (lane < 4) {
                    float v = s[lane] + bt1[j0 + lane];
                    h[(size_t)b * DD + j0 + lane] = v / (1.f + expf(-v));
                }
            }
        }
        flag_add(flag_at(flags, b, 0));
        flag_wait(flag_at(flags, b, 0), 8);
        // ---- S2: cond[rows] = Wt2 @ h + bt2
        for (int i = tid; i < DD; i += 256) xl[i] = h[(size_t)b * DD + i];
        __syncthreads();
        {
            float4 xa = reinterpret_cast<const float4*>(xl)[lane * 2];
            float4 xb = reinterpret_cast<const float4*>(xl)[lane * 2 + 1];
            for (int j0 = rows0 + wave * 16; j0 < rows0 + wave * 16 + 16; j0 += 4) {
                float s[4];
                wave_dot512x4(Wt2 + (size_t)j0 * DD, DD, xa, xb, lane, s);
                if (lane < 4)
                    cond[(size_t)b * DD + j0 + lane] = s[lane] + bt2[j0 + lane];
            }
        }
        flag_add(flag_at(flags, b, 1));
        flag_wait(flag_at(flags, b, 1), 8);
        // ---- S3: q[rows] = Wq @ (fusion + cond)
        for (int i = tid; i < DD; i += 256)
            xl[i] = fusion[(size_t)b * DD + i] + cond[(size_t)b * DD + i];
        __syncthreads();
        {
            float4 xa = reinterpret_cast<const float4*>(xl)[lane * 2];
            float4 xb = reinterpret_cast<const float4*>(xl)[lane * 2 + 1];
            for (int j0 = rows0 + wave * 16; j0 < rows0 + wave * 16 + 16; j0 += 4) {
                float s[4];
                wave_dot512x4(Wq + (size_t)j0 * DD, DD, xa, xb, lane, s);
                if (lane < 4) q[(size_t)b * DD + j0 + lane] = s[lane];
            }
        }
        flag_add(flag_at(flags, b, 2));
        flag_wait(flag_at(flags, b, 2), 8);
        // ---- S4: qk[c0..c0+64] = Wk^T @ q  (cols c0 = part*64)
        for (int i = tid; i < DD; i += 256) xl[i] = q[(size_t)b * DD + i];
        __syncthreads();
        {
            int c0 = part * 64;
            float p = 0.f;
            for (int j = wave * 128; j < wave * 128 + 128; ++j)
                p += xl[j] * Wk[(size_t)j * DD + c0 + lane];
            paux[wave][lane] = p;
            __syncthreads();
            if (tid < 64)
                qk[(size_t)b * DD + c0 + tid] =
                    paux[0][tid] + paux[1][tid] + paux[2][tid] + paux[3][tid];
        }
        return;  // kernel boundary makes qk/cond visible downstream
    }

    // ---------------- sim / argmax / gather ----------------
    int bn = blk - 256, b = bn >> 7;
    // convWb prologue spread over first 1024 sim blocks
    if (bn < 1024) {
        int idx = (bn * 256 + tid) * 2;
        int r = idx >> 9, k = idx & 511;
        float2 v = *reinterpret_cast<const float2*>(Wd1 + (size_t)r * 1024 + 512 + k);
        ushort2 o = {f2bf(v.x), f2bf(v.y)};
        *reinterpret_cast<ushort2*>(Wb + (size_t)r * 512 + k) = o;
    }
    for (int i = tid; i < DD; i += 256) xl[i] = fusion[(size_t)b * DD + i];
    __syncthreads();
    float4 xa = reinterpret_cast<const float4*>(xl)[lane * 2];
    float4 xb = reinterpret_cast<const float4*>(xl)[lane * 2 + 1];
    const float* base = tif + (size_t)bn * SS * DD;
    float bv = -INFINITY;
    int bi = 0;
    for (int s0 = wave * 16; s0 < wave * 16 + 16; s0 += 4) {
        float sv[4];
        wave_dot512x4(base + (size_t)s0 * DD, DD, xa, xb, lane, sv);
#pragma unroll
        for (int r = 0; r < 4; ++r)
            if (sv[r] > bv) { bv = sv[r]; bi = s0 + r; }  // strict >: first max
    }
    if (lane == 0) { bv_s[wave] = bv; bi_s[wave] = bi; }
    __syncthreads();
    if (tid == 0) {
        float v = bv_s[0]; int i0 = bi_s[0];
        for (int w = 1; w < 4; w++)
            if (bv_s[w] > v) { v = bv_s[w]; i0 = bi_s[w]; }  // waves ascend in s
        bidx_s = i0;
    }
    __syncthreads();
    const float* src = base + (size_t)bidx_s * DD;
    for (int i = tid; i < DD; i += 256) {
        float vv = src[i];
        tif_best[(size_t)bn * DD + i] = vv;
        abf[(size_t)bn * DD + i] = f2bf(vv);
    }
}

// k_vsum: score (qk . tif_best + x) + softmax + wout + vsum. grid (2, B).
__global__ __launch_bounds__(256) void k_vsum(
    const float* __restrict__ qk, const float* __restrict__ x,
    const float* __restrict__ tif_best, const float* __restrict__ cond,
    float* __restrict__ wout, float* __restrict__ vsum) {
    __shared__ __align__(16) float qkl[DD];
    __shared__ float wl[NN];
    __shared__ float redm[2], reds[2];
    int b = blockIdx.y, tid = threadIdx.x, lane = tid & 63, wave = tid >> 6;
    for (int i = tid; i < DD; i += 256) qkl[i] = qk[(size_t)b * DD + i];
    __syncthreads();
    {
        float4 xa = reinterpret_cast<const float4*>(qkl)[lane * 2];
        float4 xb = reinterpret_cast<const float4*>(qkl)[lane * 2 + 1];
        for (int n0 = wave * 32; n0 < wave * 32 + 32; n0 += 4) {
            float s[4];
            wave_dot512x4(tif_best + ((size_t)(b * NN + n0)) * DD, DD, xa, xb, lane, s);
            if (lane < 4) wl[n0 + lane] = s[lane] + x[b * NN + n0 + lane];
        }
    }
    __syncthreads();
    float v = 0.f;
    if (tid < NN) {
        v = wl[tid];
        float m = v;
#pragma unroll
        for (int off = 32; off; off >>= 1) m = fmaxf(m, __shfl_xor(m, off));
        if (lane == 0) redm[wave] = m;
    }
    __syncthreads();
    float m = fmaxf(redm[0], redm[1]);
    float e = 0.f;
    if (tid < NN) {
        e = expf(v - m);
        float s = e;
#pragma unroll
        for (int off = 32; off; off >>= 1) s += __shfl_xor(s, off);
        if (lane == 0) reds[wave] = s;
    }
    __syncthreads();
    if (tid < NN) wl[tid] = e;
    __syncthreads();
    float inv = 1.f / (reds[0] + reds[1]);
    if (blockIdx.x == 0 && tid < NN) wout[b * NN + tid] = wl[tid] * inv;
    int d = blockIdx.x * 256 + tid;
    const float* base = tif_best + (size_t)b * NN * DD + d;
    float s = 0.f;
#pragma unroll 8
    for (int n = 0; n < NN; n++) s += wl[n] * base[(size_t)n * DD];
    vsum[(size_t)b * DD + d] = s * inv + cond[(size_t)b * DD + d];
}

// K4: bf16 MFMA GEMM C[4096,1024] = Abf[4096,512] x Wb^T, fused u+relu+Wd2.
// Double-buffered LDS; u-prologue overlapped with stage-0 loads.
__global__ __launch_bounds__(256) void k4_mfma(
    const ushort* __restrict__ Abf, const ushort* __restrict__ Wb,
    const float* __restrict__ Wd1, const float* __restrict__ bd1,
    const float* __restrict__ ne, const float* __restrict__ Wd2,
    float* __restrict__ p_part) {
    __shared__ ushort aS[2][128 * 64];  // 2 x 16 KB
    __shared__ ushort bS[2][128 * 64];
    __shared__ __align__(16) float nel[DD];
    __shared__ float uloc[128];
    int tid = threadIdx.x, l = tid & 63, w = tid >> 6;
    int m0 = blockIdx.x * 128, n0 = blockIdx.y * 128;
    int b = blockIdx.x;  // BM=128 == N rows per batch
    int wm = w >> 1, wn = w & 1;

    for (int i = tid; i < DD; i += 256) nel[i] = ne[(size_t)b * DD + i];
    __syncthreads();
    float4 na = reinterpret_cast<const float4*>(nel)[l * 2];
    float4 nb = reinterpret_cast<const float4*>(nel)[l * 2 + 1];

#define STAGE(K0, BUF)                                                         \
    {                                                                          \
        _Pragma("unroll") for (int i = 0; i < 4; ++i) {                        \
            int L = i * 4096 + w * 1024 + l * 16;                              \
            int row = L >> 7;                                                  \
            int bo = L & 127;                                                  \
            int sb = bo ^ ((row & 7) << 4);                                    \
            const ushort* ga = Abf + (size_t)(m0 + row) * DD + (K0) + (sb >> 1); \
            const ushort* gb = Wb + (size_t)(n0 + row) * DD + (K0) + (sb >> 1);  \
            __builtin_amdgcn_global_load_lds(                                  \
                (const __attribute__((address_space(1))) void*)ga,             \
                (__attribute__((address_space(3))) void*)(aS[BUF] + i * 2048 + w * 512), \
                16, 0, 0);                                                     \
            __builtin_amdgcn_global_load_lds(                                  \
                (const __attribute__((address_space(1))) void*)gb,             \
                (__attribute__((address_space(3))) void*)(bS[BUF] + i * 2048 + w * 512), \
                16, 0, 0);                                                     \
        }                                                                      \
    }

    STAGE(0, 0);
    // u-prologue overlaps stage-0: u[r] = Wd1_a[n0+r].ne[b] + bd1[n0+r]
    for (int j0 = 0; j0 < 32; j0 += 4) {
        int r = w * 32 + j0;
        float s[4];
        wave_dot512x4(Wd1 + (size_t)(n0 + r) * 1024, 1024, na, nb, l, s);
        if (l < 4) uloc[r + l] = s[l] + bd1[n0 + r + l];
    }
    __syncthreads();

    f32x4 acc[4][4];
#pragma unroll
    for (int i = 0; i < 4; i++)
#pragma unroll
        for (int j = 0; j < 4; j++) acc[i][j] = (f32x4){0.f, 0.f, 0.f, 0.f};

    int cur = 0;
    for (int k0 = 0; k0 < DD; k0 += 64) {
        if (k0 + 64 < DD) STAGE(k0 + 64, cur ^ 1);  // prefetch into other buf
#pragma unroll
        for (int kk = 0; kk < 2; ++kk) {
            short8 af[4], bf[4];
#pragma unroll
            for (int f = 0; f < 4; ++f) {
                int ra = wm * 64 + f * 16 + (l & 15);
                int boa = (((l >> 4) * 16 + kk * 64)) ^ ((ra & 7) << 4);
                af[f] = *reinterpret_cast<const short8*>(&aS[cur][ra * 64 + (boa >> 1)]);
                int rb = wn * 64 + f * 16 + (l & 15);
                int bob = (((l >> 4) * 16 + kk * 64)) ^ ((rb & 7) << 4);
                bf[f] = *reinterpret_cast<const short8*>(&bS[cur][rb * 64 + (bob >> 1)]);
            }
#pragma unroll
            for (int fm = 0; fm < 4; ++fm)
#pragma unroll
                for (int fn = 0; fn < 4; ++fn)
                    acc[fm][fn] = __builtin_amdgcn_mfma_f32_16x16x32_bf16(
                        af[fm], bf[fn], acc[fm][fn], 0, 0, 0);
        }
        __syncthreads();
        cur ^= 1;
    }
#undef STAGE
#pragma unroll
    for (int fm = 0; fm < 4; ++fm) {
#pragma unroll
        for (int reg = 0; reg < 4; ++reg) {
            float pp = 0.f;
#pragma unroll
            for (int fn = 0; fn < 4; ++fn) {
                int rl = wn * 64 + fn * 16 + (l & 15);
                float hh = acc[fm][fn][reg] + uloc[rl];
                if (hh > 0.f) pp += Wd2[n0 + rl] * hh;
            }
#pragma unroll
            for (int off = 1; off < 16; off <<= 1) pp += __shfl_xor(pp, off);
            if ((l & 15) == 0) {
                int m = m0 + wm * 64 + fm * 16 + (l >> 4) * 4 + reg;
                p_part[(size_t)m * 16 + blockIdx.y * 2 + wn] = pp;
            }
        }
    }
}

// K5: p = sum(p_part) + bd2 + w; bitonic sort 128 descending per b.
__global__ __launch_bounds__(128) void k5_sort(
    const float* __restrict__ p_part, const float* __restrict__ wout,
    const float* __restrict__ bd2, float* __restrict__ out) {
    __shared__ float v[NN];
    int b = blockIdx.x, tid = threadIdx.x;
    int bn = b * NN + tid;
    float s = bd2[0] + wout[bn];
#pragma unroll
    for (int c = 0; c < 16; c++) s += p_part[(size_t)bn * 16 + c];
    v[tid] = s;
    __syncthreads();
    for (int k = 2; k <= NN; k <<= 1) {
        for (int j = k >> 1; j > 0; j >>= 1) {
            int ixj = tid ^ j;
            if (ixj > tid) {
                float a = v[tid], bb2 = v[ixj];
                bool desc = (tid & k) == 0;
                if (desc ? (a < bb2) : (a > bb2)) { v[tid] = bb2; v[ixj] = a; }
            }
            __syncthreads();
        }
    }
    out[bn] = v[tid];
}

extern "C" void kernel_launch(void* const* d_in, const int* in_sizes, int n_in,
                              void* d_out, int out_size, void* d_ws, size_t ws_size,
                              hipStream_t stream) {
    const float* x      = (const float*)d_in[0];
    const int*   ts     = (const int*)d_in[1];
    const float* fusion = (const float*)d_in[2];
    const float* tif    = (const float*)d_in[3];
    const float* pe     = (const float*)d_in[4];
    const float* Wq     = (const float*)d_in[5];
    const float* Wk     = (const float*)d_in[6];
    const float* Wv     = (const float*)d_in[7];
    const float* Wp     = (const float*)d_in[8];
    const float* bp     = (const float*)d_in[9];
    const float* Wt1    = (const float*)d_in[10];
    const float* bt1    = (const float*)d_in[11];
    const float* Wt2    = (const float*)d_in[12];
    const float* bt2    = (const float*)d_in[13];
    const float* Wd1    = (const float*)d_in[14];
    const float* bd1    = (const float*)d_in[15];
    const float* Wd2    = (const float*)d_in[16];
    const float* bd2    = (const float*)d_in[17];

    float* ws = (float*)d_ws;
    float* cond     = ws;                    // 16384
    float* qk       = cond + 16384;          // 16384
    float* h        = qk + 16384;            // 16384
    float* q        = h + 16384;             // 16384
    float* wout     = q + 16384;             // 4096
    float* vsum     = wout + 4096;           // 16384
    float* ve       = vsum + 16384;          // 16384
    float* ne       = ve + 16384;            // 16384
    float* p_part   = ne + 16384;            // 65536
    float* tif_best = p_part + 65536;        // 2097152 (8 MB)
    ushort* Abf     = (ushort*)(tif_best + 2097152);  // 4 MB
    ushort* Wb      = Abf + 2097152;         // 1 MB
    unsigned* flags = (unsigned*)(Wb + 524288);  // 4096 uints
    float* out = (float*)d_out;

    // zero flags via kernel (NOT SDMA memset)
    hipLaunchKernelGGL(k_init, dim3(16), dim3(256), 0, stream, flags);

    // chain helpers (256 blocks, flag-synced) + sim (4096 blocks) + convWb
    hipLaunchKernelGGL(k2_fused, dim3(256 + BB * NN), dim3(256), 0, stream,
                       ts, pe, fusion, tif, Wt1, bt1, Wt2, bt2, Wq, Wk,
                       Wd1, Wb, h, q, cond, qk, tif_best, Abf, flags);

    // score + softmax + vsum
    hipLaunchKernelGGL(k_vsum, dim3(2, BB), dim3(256), 0, stream,
                       qk, x, tif_best, cond, wout, vsum);

    // ve = Wv @ vsum ; ne = Wp @ ve + bp
    hipLaunchKernelGGL(bmv, dim3(32, BB), dim3(256), 0, stream,
                       Wv, DD, nullptr, vsum, ve, DD, 0);
    hipLaunchKernelGGL(bmv, dim3(32, BB), dim3(256), 0, stream,
                       Wp, DD, bp, ve, ne, DD, 0);

    // decode GEMM (MFMA, dbuf, u folded) + sort
    hipLaunchKernelGGL(k4_mfma, dim3(32, 8), dim3(256), 0, stream,
                       Abf, Wb, Wd1, bd1, ne, Wd2, p_part);
    hipLaunchKernelGGL(k5_sort, dim3(BB), dim3(128), 0, stream,
                       p_part, wout, bd2, out);
}

// Round 10
// 187.573 us; speedup vs baseline: 1.2634x; 1.0931x over previous
//
#include <hip/hip_runtime.h>
#include <hip/hip_bf16.h>
#include <math.h>

// Problem: B=32, N=128, S=64, D=512
// Output: [B,N] f32, each row sorted descending.
// Round 10: exact round-6 structure (best: 187us) + ONE change: k4 double-
// buffered LDS. Fusion attempts (r7 intra-block chain, r8 flag helpers+GEMM,
// r9 flag helpers only) all measured SLOWER than plain launch gaps — device-
// side orchestration loses to ~2-3us replay-graph launch tax on this shape.

#define BB 32
#define NN 128
#define SS 64
#define DD 512

typedef __attribute__((ext_vector_type(8))) short short8;
typedef __attribute__((ext_vector_type(4))) float f32x4;

__device__ __forceinline__ ushort f2bf(float f) {
    unsigned u = __float_as_uint(f);
    unsigned r = (u + 0x7fffu + ((u >> 16) & 1u)) >> 16;
    return (ushort)r;
}

// Batched wave-dot: 4 rows of W (stride ldw) dotted with x (in regs xa/xb).
// All 8 row-loads issued before the serial shuffle reduces.
__device__ __forceinline__ void wave_dot512x4(
    const float* __restrict__ w, size_t ldw, float4 xa, float4 xb,
    int lane, float out[4]) {
    float4 ra[4], rb[4];
#pragma unroll
    for (int r = 0; r < 4; ++r) {
        const float4* row = reinterpret_cast<const float4*>(w + (size_t)r * ldw);
        ra[r] = row[lane * 2];
        rb[r] = row[lane * 2 + 1];
    }
#pragma unroll
    for (int r = 0; r < 4; ++r) {
        float s = ra[r].x * xa.x + ra[r].y * xa.y + ra[r].z * xa.z + ra[r].w * xa.w
                + rb[r].x * xb.x + rb[r].y * xb.y + rb[r].z * xb.z + rb[r].w * xb.w;
#pragma unroll
        for (int off = 32; off; off >>= 1) s += __shfl_xor(s, off);
        out[r] = s;
    }
}

// Batched matvec: Y[b][j] = act(W[j][:512] . X[b] + bias[j])
// grid (R/16, B), block 256 (4 waves x 4 rows each).
// mode 0: X = Xa[b] ; mode 1: X = pe[ts[b]] ; mode 2: X = Xa[b] + Xb[b]
__global__ __launch_bounds__(256) void bmv(
    const float* __restrict__ W, int ldw, const float* __restrict__ bias,
    const float* __restrict__ Xa, const float* __restrict__ Xb,
    const int* __restrict__ ts, const float* __restrict__ pe,
    float* __restrict__ Y, int R, int act, int mode) {
    __shared__ __align__(16) float xl[DD];
    int b = blockIdx.y, tid = threadIdx.x, lane = tid & 63, wave = tid >> 6;
    const float* src = (mode == 1) ? (pe + (size_t)ts[b] * DD) : (Xa + (size_t)b * DD);
    if (mode == 2) {
        const float* s2 = Xb + (size_t)b * DD;
        for (int i = tid; i < DD; i += 256) xl[i] = src[i] + s2[i];
    } else {
        for (int i = tid; i < DD; i += 256) xl[i] = src[i];
    }
    __syncthreads();
    float4 xa = reinterpret_cast<const float4*>(xl)[lane * 2];
    float4 xb = reinterpret_cast<const float4*>(xl)[lane * 2 + 1];
    int j0 = blockIdx.x * 16 + wave * 4;
    float s[4];
    wave_dot512x4(W + (size_t)j0 * ldw, ldw, xa, xb, lane, s);
    if (lane < 4) {
        int j = j0 + lane;
        float v = s[lane];
        if (bias) v += bias[j];
        if (act == 1) v = v / (1.f + expf(-v));  // silu
        Y[(size_t)b * R + j] = v;
    }
}

// qk[b][c] = sum_j q[b][j] * Wk[j][c]   (transposed matvec)
__global__ __launch_bounds__(256) void k_qk(
    const float* __restrict__ Wk, const float* __restrict__ q,
    float* __restrict__ qk) {
    __shared__ __align__(16) float ql[DD];
    __shared__ float part[4][64];
    int b = blockIdx.y, c0 = blockIdx.x * 64;
    int tid = threadIdx.x, lane = tid & 63, wave = tid >> 6;
    for (int i = tid; i < DD; i += 256) ql[i] = q[(size_t)b * DD + i];
    __syncthreads();
    float p = 0.f;
    for (int j = wave * 128; j < wave * 128 + 128; ++j)
        p += ql[j] * Wk[(size_t)j * DD + c0 + lane];
    part[wave][lane] = p;
    __syncthreads();
    if (tid < 64)
        qk[(size_t)b * DD + c0 + tid] =
            part[0][tid] + part[1][tid] + part[2][tid] + part[3][tid];
}

// K2: per (b,n): sim over S (4-row batched loads), argmax, gather best row
// (f32 + bf16), raw score (free in-register dot with qk during the gather).
// Blocks < 1024 also convert Wd1 right half to bf16.
__global__ __launch_bounds__(256) void k2_sim(
    const float* __restrict__ fusion, const float* __restrict__ tif,
    const float* __restrict__ x, const float* __restrict__ qk,
    const float* __restrict__ Wd1, ushort* __restrict__ Wb,
    float* __restrict__ tif_best, ushort* __restrict__ abf,
    float* __restrict__ score) {
    __shared__ __align__(16) float fb[DD];
    __shared__ float bv_s[4];
    __shared__ int bi_s[4];
    __shared__ int bidx_s;
    __shared__ float dred[4];
    int bn = blockIdx.x, b = bn >> 7;
    int tid = threadIdx.x, lane = tid & 63, wave = tid >> 6;

    // convWb prologue: 1024 blocks x 256 thr x 2 elems = 524288 elems
    if (bn < 1024) {
        int idx = (bn * 256 + tid) * 2;
        int r = idx >> 9, k = idx & 511;
        float2 v = *reinterpret_cast<const float2*>(Wd1 + (size_t)r * 1024 + 512 + k);
        ushort2 o = {f2bf(v.x), f2bf(v.y)};
        *reinterpret_cast<ushort2*>(Wb + (size_t)r * 512 + k) = o;
    }

    for (int i = tid; i < DD; i += 256) fb[i] = fusion[(size_t)b * DD + i];
    __syncthreads();
    float4 xa = reinterpret_cast<const float4*>(fb)[lane * 2];
    float4 xb = reinterpret_cast<const float4*>(fb)[lane * 2 + 1];
    const float* base = tif + (size_t)bn * SS * DD;
    float bv = -INFINITY;
    int bi = 0;
    for (int s0 = wave * 16; s0 < wave * 16 + 16; s0 += 4) {
        float sv[4];
        wave_dot512x4(base + (size_t)s0 * DD, DD, xa, xb, lane, sv);
#pragma unroll
        for (int r = 0; r < 4; ++r)
            if (sv[r] > bv) { bv = sv[r]; bi = s0 + r; }  // strict >: first max
    }
    if (lane == 0) { bv_s[wave] = bv; bi_s[wave] = bi; }
    __syncthreads();
    if (tid == 0) {
        float v = bv_s[0]; int i0 = bi_s[0];
        for (int w = 1; w < 4; w++)
            if (bv_s[w] > v) { v = bv_s[w]; i0 = bi_s[w]; }  // waves ascend in s
        bidx_s = i0;
    }
    __syncthreads();
    const float* src = base + (size_t)bidx_s * DD;
    const float* qkb = qk + (size_t)b * DD;
    float local = 0.f;
    for (int i = tid; i < DD; i += 256) {
        float vv = src[i];
        tif_best[(size_t)bn * DD + i] = vv;
        abf[(size_t)bn * DD + i] = f2bf(vv);
        local += vv * qkb[i];
    }
#pragma unroll
    for (int off = 32; off; off >>= 1) local += __shfl_xor(local, off);
    if (lane == 0) dred[wave] = local;
    __syncthreads();
    if (tid == 0) score[bn] = dred[0] + dred[1] + dred[2] + dred[3] + x[bn];
}

// vsum (softmax fused, computed redundantly per block). grid (2, B), block 256.
__global__ __launch_bounds__(256) void k_vsum(
    const float* __restrict__ score, const float* __restrict__ tif_best,
    const float* __restrict__ cond,
    float* __restrict__ wout, float* __restrict__ vsum) {
    __shared__ float wl[NN];
    __shared__ float redm[2], reds[2];
    int b = blockIdx.y, tid = threadIdx.x, lane = tid & 63, wave = tid >> 6;
    float v = 0.f;
    if (tid < NN) {
        v = score[b * NN + tid];
        float m = v;
#pragma unroll
        for (int off = 32; off; off >>= 1) m = fmaxf(m, __shfl_xor(m, off));
        if (lane == 0) redm[wave] = m;
    }
    __syncthreads();
    float m = fmaxf(redm[0], redm[1]);
    if (tid < NN) {
        float e = expf(v - m);
        wl[tid] = e;
        float s = e;
#pragma unroll
        for (int off = 32; off; off >>= 1) s += __shfl_xor(s, off);
        if (lane == 0) reds[wave] = s;
    }
    __syncthreads();
    float inv = 1.f / (reds[0] + reds[1]);
    if (blockIdx.x == 0 && tid < NN) wout[b * NN + tid] = wl[tid] * inv;
    int d = blockIdx.x * 256 + tid;
    const float* base = tif_best + (size_t)b * NN * DD + d;
    float s = 0.f;
#pragma unroll 8
    for (int n = 0; n < NN; n++) s += wl[n] * base[(size_t)n * DD];
    vsum[(size_t)b * DD + d] = s * inv + cond[(size_t)b * DD + d];
}

// K4: bf16 MFMA GEMM C[4096,1024] = Abf[4096,512] x Wb^T, fused u+relu+Wd2.
// Double-buffered LDS: STAGE(next, buf^1) issued BEFORE compute(buf); one
// barrier per K-step. u-prologue overlapped with stage-0 loads.
__global__ __launch_bounds__(256) void k4_mfma(
    const ushort* __restrict__ Abf, const ushort* __restrict__ Wb,
    const float* __restrict__ Wd1, const float* __restrict__ bd1,
    const float* __restrict__ ne, const float* __restrict__ Wd2,
    float* __restrict__ p_part) {
    __shared__ ushort aS[2][128 * 64];  // 2 x 16 KB
    __shared__ ushort bS[2][128 * 64];
    __shared__ __align__(16) float nel[DD];
    __shared__ float uloc[128];
    int tid = threadIdx.x, l = tid & 63, w = tid >> 6;
    int m0 = blockIdx.x * 128, n0 = blockIdx.y * 128;
    int b = blockIdx.x;  // BM=128 == N rows per batch
    int wm = w >> 1, wn = w & 1;

    for (int i = tid; i < DD; i += 256) nel[i] = ne[(size_t)b * DD + i];
    __syncthreads();
    float4 na = reinterpret_cast<const float4*>(nel)[l * 2];
    float4 nb = reinterpret_cast<const float4*>(nel)[l * 2 + 1];

#define STAGE(K0, BUF)                                                         \
    {                                                                          \
        _Pragma("unroll") for (int i = 0; i < 4; ++i) {                        \
            int L = i * 4096 + w * 1024 + l * 16;                              \
            int row = L >> 7;                                                  \
            int bo = L & 127;                                                  \
            int sb = bo ^ ((row & 7) << 4);                                    \
            const ushort* ga = Abf + (size_t)(m0 + row) * DD + (K0) + (sb >> 1); \
            const ushort* gb = Wb + (size_t)(n0 + row) * DD + (K0) + (sb >> 1);  \
            __builtin_amdgcn_global_load_lds(                                  \
                (const __attribute__((address_space(1))) void*)ga,             \
                (__attribute__((address_space(3))) void*)(aS[BUF] + i * 2048 + w * 512), \
                16, 0, 0);                                                     \
            __builtin_amdgcn_global_load_lds(                                  \
                (const __attribute__((address_space(1))) void*)gb,             \
                (__attribute__((address_space(3))) void*)(bS[BUF] + i * 2048 + w * 512), \
                16, 0, 0);                                                     \
        }                                                                      \
    }

    STAGE(0, 0);
    // u-prologue overlaps stage-0: u[r] = Wd1_a[n0+r].ne[b] + bd1[n0+r]
    for (int j0 = 0; j0 < 32; j0 += 4) {
        int r = w * 32 + j0;
        float s[4];
        wave_dot512x4(Wd1 + (size_t)(n0 + r) * 1024, 1024, na, nb, l, s);
        if (l < 4) uloc[r + l] = s[l] + bd1[n0 + r + l];
    }
    __syncthreads();

    f32x4 acc[4][4];
#pragma unroll
    for (int i = 0; i < 4; i++)
#pragma unroll
        for (int j = 0; j < 4; j++) acc[i][j] = (f32x4){0.f, 0.f, 0.f, 0.f};

    int cur = 0;
    for (int k0 = 0; k0 < DD; k0 += 64) {
        if (k0 + 64 < DD) STAGE(k0 + 64, cur ^ 1);  // prefetch into other buf
#pragma unroll
        for (int kk = 0; kk < 2; ++kk) {
            short8 af[4], bf[4];
#pragma unroll
            for (int f = 0; f < 4; ++f) {
                int ra = wm * 64 + f * 16 + (l & 15);
                int boa = (((l >> 4) * 16 + kk * 64)) ^ ((ra & 7) << 4);
                af[f] = *reinterpret_cast<const short8*>(&aS[cur][ra * 64 + (boa >> 1)]);
                int rb = wn * 64 + f * 16 + (l & 15);
                int bob = (((l >> 4) * 16 + kk * 64)) ^ ((rb & 7) << 4);
                bf[f] = *reinterpret_cast<const short8*>(&bS[cur][rb * 64 + (bob >> 1)]);
            }
#pragma unroll
            for (int fm = 0; fm < 4; ++fm)
#pragma unroll
                for (int fn = 0; fn < 4; ++fn)
                    acc[fm][fn] = __builtin_amdgcn_mfma_f32_16x16x32_bf16(
                        af[fm], bf[fn], acc[fm][fn], 0, 0, 0);
        }
        __syncthreads();  // buf[cur] consumed; next-tile loads drained
        cur ^= 1;
    }
#undef STAGE
#pragma unroll
    for (int fm = 0; fm < 4; ++fm) {
#pragma unroll
        for (int reg = 0; reg < 4; ++reg) {
            float pp = 0.f;
#pragma unroll
            for (int fn = 0; fn < 4; ++fn) {
                int rl = wn * 64 + fn * 16 + (l & 15);
                float hh = acc[fm][fn][reg] + uloc[rl];
                if (hh > 0.f) pp += Wd2[n0 + rl] * hh;
            }
#pragma unroll
            for (int off = 1; off < 16; off <<= 1) pp += __shfl_xor(pp, off);
            if ((l & 15) == 0) {
                int m = m0 + wm * 64 + fm * 16 + (l >> 4) * 4 + reg;
                p_part[(size_t)m * 16 + blockIdx.y * 2 + wn] = pp;
            }
        }
    }
}

// K5: p = sum(p_part) + bd2 + w; bitonic sort 128 descending per b.
__global__ __launch_bounds__(128) void k5_sort(
    const float* __restrict__ p_part, const float* __restrict__ wout,
    const float* __restrict__ bd2, float* __restrict__ out) {
    __shared__ float v[NN];
    int b = blockIdx.x, tid = threadIdx.x;
    int bn = b * NN + tid;
    float s = bd2[0] + wout[bn];
#pragma unroll
    for (int c = 0; c < 16; c++) s += p_part[(size_t)bn * 16 + c];
    v[tid] = s;
    __syncthreads();
    for (int k = 2; k <= NN; k <<= 1) {
        for (int j = k >> 1; j > 0; j >>= 1) {
            int ixj = tid ^ j;
            if (ixj > tid) {
                float a = v[tid], bb2 = v[ixj];
                bool desc = (tid & k) == 0;
                if (desc ? (a < bb2) : (a > bb2)) { v[tid] = bb2; v[ixj] = a; }
            }
            __syncthreads();
        }
    }
    out[bn] = v[tid];
}

extern "C" void kernel_launch(void* const* d_in, const int* in_sizes, int n_in,
                              void* d_out, int out_size, void* d_ws, size_t ws_size,
                              hipStream_t stream) {
    const float* x      = (const float*)d_in[0];
    const int*   ts     = (const int*)d_in[1];
    const float* fusion = (const float*)d_in[2];
    const float* tif    = (const float*)d_in[3];
    const float* pe     = (const float*)d_in[4];
    const float* Wq     = (const float*)d_in[5];
    const float* Wk     = (const float*)d_in[6];
    const float* Wv     = (const float*)d_in[7];
    const float* Wp     = (const float*)d_in[8];
    const float* bp     = (const float*)d_in[9];
    const float* Wt1    = (const float*)d_in[10];
    const float* bt1    = (const float*)d_in[11];
    const float* Wt2    = (const float*)d_in[12];
    const float* bt2    = (const float*)d_in[13];
    const float* Wd1    = (const float*)d_in[14];
    const float* bd1    = (const float*)d_in[15];
    const float* Wd2    = (const float*)d_in[16];
    const float* bd2    = (const float*)d_in[17];

    float* ws = (float*)d_ws;
    float* cond     = ws;                    // 16384
    float* qk       = cond + 16384;          // 16384
    float* h        = qk + 16384;            // 16384
    float* q        = h + 16384;             // 16384
    float* score    = q + 16384;             // 4096
    float* wout     = score + 4096;          // 4096
    float* vsum     = wout + 4096;           // 16384
    float* ve       = vsum + 16384;          // 16384
    float* ne       = ve + 16384;            // 16384
    float* p_part   = ne + 16384;            // 65536
    float* tif_best = p_part + 65536;        // 2097152 (8 MB)
    ushort* Abf     = (ushort*)(tif_best + 2097152);  // 4 MB
    ushort* Wb      = Abf + 2097152;         // 1 MB
    float* out = (float*)d_out;

    // cond chain (grid-parallel over rows x batch)
    hipLaunchKernelGGL(bmv, dim3(32, BB), dim3(256), 0, stream,
                       Wt1, DD, bt1, nullptr, nullptr, ts, pe, h, DD, 1, 1);
    hipLaunchKernelGGL(bmv, dim3(32, BB), dim3(256), 0, stream,
                       Wt2, DD, bt2, h, nullptr, nullptr, nullptr, cond, DD, 0, 0);
    hipLaunchKernelGGL(bmv, dim3(32, BB), dim3(256), 0, stream,
                       Wq, DD, nullptr, fusion, cond, nullptr, nullptr, q, DD, 0, 2);
    hipLaunchKernelGGL(k_qk, dim3(8, BB), dim3(256), 0, stream, Wk, q, qk);

    // the 537MB streamer (+ convWb prologue, + free in-register score)
    hipLaunchKernelGGL(k2_sim, dim3(BB * NN), dim3(256), 0, stream,
                       fusion, tif, x, qk, Wd1, Wb, tif_best, Abf, score);

    // attention chain
    hipLaunchKernelGGL(k_vsum, dim3(2, BB), dim3(256), 0, stream,
                       score, tif_best, cond, wout, vsum);
    hipLaunchKernelGGL(bmv, dim3(32, BB), dim3(256), 0, stream,
                       Wv, DD, nullptr, vsum, nullptr, nullptr, nullptr, ve, DD, 0, 0);
    hipLaunchKernelGGL(bmv, dim3(32, BB), dim3(256), 0, stream,
                       Wp, DD, bp, ve, nullptr, nullptr, nullptr, ne, DD, 0, 0);

    // decode GEMM (MFMA, dbuf, u folded) + sort
    hipLaunchKernelGGL(k4_mfma, dim3(32, 8), dim3(256), 0, stream,
                       Abf, Wb, Wd1, bd1, ne, Wd2, p_part);
    hipLaunchKernelGGL(k5_sort, dim3(BB), dim3(128), 0, stream,
                       p_part, wout, bd2, out);
}